// Round 6
// baseline (440.789 us; speedup 1.0000x reference)
//
#include <hip/hip_runtime.h>
#include <hip/hip_bf16.h>
#include <math.h>

#define D_MODEL 512
#define NHEAD   8
#define HEAD_DIM 64
#define BB      8
#define NN      1024
#define NS      1
#define TI      16
#define TJ      32
#define NT      (NN / TJ)
#define FIX_M   10.0f
#define GSTRIDE 40   // LDS row stride (shorts) for MFMA gemm tiles

typedef __attribute__((ext_vector_type(8))) short short8;
typedef __attribute__((ext_vector_type(4))) float floatx4;

// gelu, tanh form: 0.5x(1+tanh(0.79788(x+0.044715x^3))) = x*(1 - 1/(1+e^{2y}))
// 8 VALU ops, branch-free; |err vs erf-gelu| <= ~1e-3 absolute.
__device__ __forceinline__ float gelu_tanh(float x) {
    const float x2 = x * x;
    const float z  = x * fmaf(0.0713548162f, x2, 1.5957691216f);  // 2y
    const float e  = __expf(z);
    const float r  = __builtin_amdgcn_rcpf(1.0f + e);
    return fmaf(-x, r, x);
}

__device__ __forceinline__ unsigned short f2bf(float f) {
    unsigned u = __float_as_uint(f);
    u = (u + 0x7fffu + ((u >> 16) & 1u)) >> 16;   // RNE
    return (unsigned short)u;
}

__device__ __forceinline__ uint2 pack4bf(float a, float b, float c, float d) {
    uint2 p;
    p.x = (unsigned)f2bf(a) | ((unsigned)f2bf(b) << 16);
    p.y = (unsigned)f2bf(c) | ((unsigned)f2bf(d) << 16);
    return p;
}

// ---------------- bf16 MFMA GEMM: qkv = x @ qkv_w^T, fused bf16 epilogue ----
__global__ __launch_bounds__(256)
void gemm_qkv_mfma(const float* __restrict__ A, const float* __restrict__ Bm,
                   unsigned short* __restrict__ Qb, unsigned short* __restrict__ Kb,
                   unsigned short* __restrict__ Vt) {
    __shared__ __align__(16) unsigned short As[128 * GSTRIDE];
    __shared__ __align__(16) unsigned short Bs[128 * GSTRIDE];
    const int tid = threadIdx.x;
    const int bm = blockIdx.y * 128;
    const int bn = blockIdx.x * 128;
    const int wv = tid >> 6, lane = tid & 63, quad = lane >> 4, ln = lane & 15;
    const int wm = (wv >> 1) * 64, wn = (wv & 1) * 64;

    floatx4 acc[4][4];
    #pragma unroll
    for (int i = 0; i < 4; ++i)
        #pragma unroll
        for (int j = 0; j < 4; ++j) acc[i][j] = (floatx4){0.f, 0.f, 0.f, 0.f};

    for (int k0 = 0; k0 < 512; k0 += 32) {
        __syncthreads();
        #pragma unroll
        for (int t = 0; t < 4; ++t) {
            const int c = tid + t * 256;
            const int row = c >> 3, kc = (c & 7) * 4;
            float4 v = *(const float4*)(A + (size_t)(bm + row) * 512 + k0 + kc);
            *(uint2*)&As[row * GSTRIDE + kc] = pack4bf(v.x, v.y, v.z, v.w);
            float4 w = *(const float4*)(Bm + (size_t)(bn + row) * 512 + k0 + kc);
            *(uint2*)&Bs[row * GSTRIDE + kc] = pack4bf(w.x, w.y, w.z, w.w);
        }
        __syncthreads();
        short8 af[4], bf[4];
        #pragma unroll
        for (int mb = 0; mb < 4; ++mb)
            af[mb] = *(const short8*)&As[(wm + mb * 16 + ln) * GSTRIDE + quad * 8];
        #pragma unroll
        for (int nb = 0; nb < 4; ++nb)
            bf[nb] = *(const short8*)&Bs[(wn + nb * 16 + ln) * GSTRIDE + quad * 8];
        #pragma unroll
        for (int mb = 0; mb < 4; ++mb)
            #pragma unroll
            for (int nb = 0; nb < 4; ++nb)
                acc[mb][nb] = __builtin_amdgcn_mfma_f32_16x16x32_bf16(af[mb], bf[nb], acc[mb][nb], 0, 0, 0);
    }

    #pragma unroll
    for (int nb = 0; nb < 4; ++nb) {
        const int n = bn + wn + nb * 16 + ln;
        #pragma unroll
        for (int mb = 0; mb < 4; ++mb) {
            const int m = bm + wm + mb * 16 + quad * 4;
            if (n < 512) {
                #pragma unroll
                for (int r = 0; r < 4; ++r)
                    Qb[(size_t)(m + r) * 512 + n] = f2bf(acc[mb][nb][r] * 0.125f);
            } else if (n < 1024) {
                #pragma unroll
                for (int r = 0; r < 4; ++r)
                    Kb[(size_t)(m + r) * 512 + (n - 512)] = f2bf(acc[mb][nb][r]);
            } else {
                const int bb = m >> 10, tok = m & 1023;
                *(uint2*)(Vt + ((size_t)bb * 512 + (n - 1024)) * NN + tok) =
                    pack4bf(acc[mb][nb][0], acc[mb][nb][1], acc[mb][nb][2], acc[mb][nb][3]);
            }
        }
    }
}

// ---------------- bf16 MFMA GEMM: out = attn_out(bf16) @ out_w^T + out_b ----
__global__ __launch_bounds__(256)
void gemm_out_mfma(const unsigned short* __restrict__ Ab, const float* __restrict__ Bm,
                   const float* __restrict__ bias, float* __restrict__ C) {
    __shared__ __align__(16) unsigned short As[128 * GSTRIDE];
    __shared__ __align__(16) unsigned short Bs[128 * GSTRIDE];
    const int tid = threadIdx.x;
    const int bm = blockIdx.y * 128;
    const int bn = blockIdx.x * 128;
    const int wv = tid >> 6, lane = tid & 63, quad = lane >> 4, ln = lane & 15;
    const int wm = (wv >> 1) * 64, wn = (wv & 1) * 64;

    floatx4 acc[4][4];
    #pragma unroll
    for (int i = 0; i < 4; ++i)
        #pragma unroll
        for (int j = 0; j < 4; ++j) acc[i][j] = (floatx4){0.f, 0.f, 0.f, 0.f};

    for (int k0 = 0; k0 < 512; k0 += 32) {
        __syncthreads();
        #pragma unroll
        for (int t = 0; t < 4; ++t) {
            const int c = tid + t * 256;
            const int row = c >> 3, kc = (c & 7) * 4;
            *(uint2*)&As[row * GSTRIDE + kc] =
                *(const uint2*)(Ab + (size_t)(bm + row) * 512 + k0 + kc);
            float4 w = *(const float4*)(Bm + (size_t)(bn + row) * 512 + k0 + kc);
            *(uint2*)&Bs[row * GSTRIDE + kc] = pack4bf(w.x, w.y, w.z, w.w);
        }
        __syncthreads();
        short8 af[4], bf[4];
        #pragma unroll
        for (int mb = 0; mb < 4; ++mb)
            af[mb] = *(const short8*)&As[(wm + mb * 16 + ln) * GSTRIDE + quad * 8];
        #pragma unroll
        for (int nb = 0; nb < 4; ++nb)
            bf[nb] = *(const short8*)&Bs[(wn + nb * 16 + ln) * GSTRIDE + quad * 8];
        #pragma unroll
        for (int mb = 0; mb < 4; ++mb)
            #pragma unroll
            for (int nb = 0; nb < 4; ++nb)
                acc[mb][nb] = __builtin_amdgcn_mfma_f32_16x16x32_bf16(af[mb], bf[nb], acc[mb][nb], 0, 0, 0);
    }

    #pragma unroll
    for (int nb = 0; nb < 4; ++nb) {
        const int n = bn + wn + nb * 16 + ln;
        const float bv = bias[n];
        #pragma unroll
        for (int mb = 0; mb < 4; ++mb) {
            const int m = bm + wm + mb * 16 + quad * 4;
            #pragma unroll
            for (int r = 0; r < 4; ++r)
                C[(size_t)(m + r) * 512 + n] = acc[mb][nb][r] + bv;
        }
    }
}

// ---------------- MFMA flash attention: one head per wave --------------------
// Block = (b, 16 queries); 512 thr = 8 waves; wave wv owns head h=wv over ALL
// 32 j-tiles (no j-split -> no partial combine), and computes MLP rows
// i in {2wv, 2wv+1} (8 waves x 2 = 16 rows; total MLP work unchanged vs R0).
// WHY (R5 post-mortem): R5's per-wave footprint (VGPR 124 + ~32 AGPR oacc)
// exceeded the 128-reg granule, so a second 8-wave block could not co-reside
// (occupancy 23.6% = 1 block) and every barrier stalled the whole CU. This
// layout halves kf/vf (one head: 32 regs), halves oacc (16) and qf (8):
// data-live ~96 -> fits the 128 cap that 4 waves/SIMD needs.
// launch_bounds(512,4): k = 4*4/8 = 2 blocks/CU -> 16 waves/CU target; LDS
// 28 KB/block is far under the limit, so registers set residency.
// Protocol is the VERIFIED R0 body: bias double-buffer + ONE barrier/iter
// (8 participants now), identical ps fence idiom (rule #18), full 16-row
// MFMAs, no row duplication (the R1/R4 failure pattern is absent).
__global__ __launch_bounds__(512, 4)
void attn_kernel(const unsigned short* __restrict__ Qb,
                 const unsigned short* __restrict__ Kb,
                 const unsigned short* __restrict__ Vt,
                 const float* __restrict__ coords,
                 const unsigned char* __restrict__ mask,
                 const float* __restrict__ w1, const float* __restrict__ b1,
                 const float* __restrict__ w2, const float* __restrict__ b2,
                 const float* __restrict__ coord_scales,
                 const float* __restrict__ alpha_p,
                 unsigned short* __restrict__ attn_out) {
    const int b   = blockIdx.y;
    const int i0  = blockIdx.x * TI;
    const int tid = threadIdx.x;
    const int wv  = tid >> 6;        // 0..7 = this wave's head
    const int lane = tid & 63;
    const int quad = lane >> 4;
    const int ln   = lane & 15;
    const int h    = wv;

    __shared__ _Float16 bias_s[2][TI][TJ][9];                   // 18.0 KB
    __shared__ __align__(16) unsigned short ps[NHEAD][16][40];  // 10.0 KB

    const float alpha = alpha_p[0];
    const float isx = 1.0f / coord_scales[0];
    const float isy = 1.0f / coord_scales[1];
    const float isz = 1.0f / coord_scales[2];

    // this wave's 2 MLP query coords in registers (loop-invariant)
    float cir[2][3];
    #pragma unroll
    for (int g = 0; g < 2; ++g) {
        const float* cp = coords + ((size_t)b * NN + i0 + wv * 2 + g) * 3;
        cir[g][0] = cp[0] * isx; cir[g][1] = cp[1] * isy; cir[g][2] = cp[2] * isz;
    }

    // ---- per-lane MLP weight slice: units ku = quad*8+jj ----
    float4 w1r[8]; float b1r[8];
    #pragma unroll
    for (int jj = 0; jj < 8; ++jj) {
        w1r[jj] = *(const float4*)(w1 + (quad * 8 + jj) * 4);
        b1r[jj] = b1[quad * 8 + jj];
    }
    // w2 B-fragment: B[n=ln(head)][k=quad*8+jj] = alpha*w2, heads 8..15 -> 0
    short8 b2f;
    #pragma unroll
    for (int jj = 0; jj < 8; ++jj) {
        const float v = (ln < 8) ? alpha * w2[ln * 32 + quad * 8 + jj] : 0.0f;
        b2f[jj] = (short)f2bf(v);
    }
    const float ab2 = (ln < 8) ? alpha * b2[ln] : 0.0f;

    // Q A-fragments for this head (bf16, pre-scaled by 0.125)
    short8 qf[2];
    #pragma unroll
    for (int kd = 0; kd < 2; ++kd)
        qf[kd] = *(const short8*)(Qb + ((size_t)b * NN + i0 + ln) * 512
                                  + h * 64 + kd * 32 + quad * 8);

    floatx4 oacc[4];
    #pragma unroll
    for (int nd = 0; nd < 4; ++nd) oacc[nd] = (floatx4){0.f, 0.f, 0.f, 0.f};
    float l_part[4];
    #pragma unroll
    for (int r = 0; r < 4; ++r) l_part[r] = 0.f;

    const unsigned char* maskp = mask + (size_t)b * NN;
    float cjx[2], cjy[2], cjz[2];

    #define LOAD_CJ(tt_) do { const int tt = (tt_);                               \
        if (tt < NT) {                                                            \
            const float* cp0 = coords + ((size_t)b * NN + tt * TJ + ln) * 3;      \
            cjx[0] = cp0[0] * isx; cjy[0] = cp0[1] * isy; cjz[0] = cp0[2] * isz;  \
            cjx[1] = cp0[48] * isx; cjy[1] = cp0[49] * isy; cjz[1] = cp0[50] * isz; \
        } } while (0)

    // MLP for tile tt -> bias_s[tt&1]; 2 i-rows x 2 j-halves per wave.
    #define MLP_TILE(tt_) do { const int tt = (tt_);                              \
        if (tt < NT) {                                                            \
            const int pbw = tt & 1;                                               \
            const int j0m = tt * TJ;                                              \
            _Pragma("unroll")                                                     \
            for (int g = 0; g < 2; ++g) {                                         \
                const int i = wv * 2 + g;                                         \
                const float cix = cir[g][0], ciy = cir[g][1], ciz = cir[g][2];    \
                const bool irow0 = (i0 + i < NS);                                 \
                _Pragma("unroll")                                                 \
                for (int jh = 0; jh < 2; ++jh) {                                  \
                    const float dx = cix - cjx[jh];                               \
                    const float dy = ciy - cjy[jh];                               \
                    const float dz = ciz - cjz[jh];                               \
                    const float dist = sqrtf(dx * dx + dy * dy + dz * dz);        \
                    float hu[8];                                                  \
                    _Pragma("unroll")                                             \
                    for (int jj = 0; jj < 8; ++jj) {                              \
                        const float4 wa = w1r[jj];                                \
                        float t0v = fmaf(wa.x, dx, fmaf(wa.y, dy,                 \
                                    fmaf(wa.z, dz, fmaf(wa.w, dist, b1r[jj]))));  \
                        hu[jj] = gelu_tanh(t0v);                                  \
                    }                                                             \
                    union { short8 s8; unsigned u4[4]; } H;                       \
                    _Pragma("unroll")                                             \
                    for (int k = 0; k < 4; ++k) {                                 \
                        __hip_bfloat162 t2 = __float22bfloat162_rn(               \
                            make_float2(hu[2 * k], hu[2 * k + 1]));               \
                        H.u4[k] = *(unsigned*)&t2;                                \
                    }                                                             \
                    floatx4 D = __builtin_amdgcn_mfma_f32_16x16x32_bf16(          \
                        H.s8, b2f, (floatx4){0.f, 0.f, 0.f, 0.f}, 0, 0, 0);       \
                    if (ln < 8) {                                                 \
                        _Pragma("unroll")                                         \
                        for (int r = 0; r < 4; ++r) {                             \
                            const int jw = jh * 16 + quad * 4 + r;                \
                            const float val = (irow0 || (j0m + jw < NS))          \
                                              ? 0.0f : (D[r] + ab2);              \
                            bias_s[pbw][i][jw][ln] = (_Float16)val;               \
                        }                                                         \
                    }                                                             \
                }                                                                 \
            }                                                                     \
        } } while (0)

    // ---- prologue ----
    LOAD_CJ(0);
    MLP_TILE(0);
    __syncthreads();              // bias_s[0] ready

    for (int jt = 0; jt < NT; ++jt) {
        const int j0 = jt * TJ;
        const int pb = jt & 1;

        // ---- K/V/mask global loads for tile jt, this head (fly under MLP) ----
        short8 kf[4], vf[4];
        {
            const unsigned short* kbase = Kb + ((size_t)b * NN + j0) * 512 + h * 64;
            kf[0] = *(const short8*)(kbase + (size_t)ln * 512 + quad * 8);
            kf[1] = *(const short8*)(kbase + (size_t)ln * 512 + 32 + quad * 8);
            kf[2] = *(const short8*)(kbase + (size_t)(16 + ln) * 512 + quad * 8);
            kf[3] = *(const short8*)(kbase + (size_t)(16 + ln) * 512 + 32 + quad * 8);
            const unsigned short* vbase = Vt + ((size_t)b * 512 + h * 64) * NN + j0 + quad * 8;
            #pragma unroll
            for (int nd = 0; nd < 4; ++nd)
                vf[nd] = *(const short8*)(vbase + (size_t)(nd * 16 + ln) * NN);
        }
        const unsigned char mm0 = maskp[j0 + ln];
        const unsigned char mm1 = maskp[j0 + 16 + ln];

        // ---- MLP for tile jt+1 -> bias_s[(jt+1)&1] ----
        LOAD_CJ(jt + 1);
        MLP_TILE(jt + 1);

        // ---- QK mfma + bias + exp -> ps (reads bias_s[jt&1]; within-wave ps) ----
        {
            floatx4 s0 = (floatx4){0.f, 0.f, 0.f, 0.f};
            floatx4 s1 = (floatx4){0.f, 0.f, 0.f, 0.f};
            s0 = __builtin_amdgcn_mfma_f32_16x16x32_bf16(qf[0], kf[0], s0, 0, 0, 0);
            s0 = __builtin_amdgcn_mfma_f32_16x16x32_bf16(qf[1], kf[1], s0, 0, 0, 0);
            s1 = __builtin_amdgcn_mfma_f32_16x16x32_bf16(qf[0], kf[2], s1, 0, 0, 0);
            s1 = __builtin_amdgcn_mfma_f32_16x16x32_bf16(qf[1], kf[3], s1, 0, 0, 0);
            #pragma unroll
            for (int r = 0; r < 4; ++r) {
                const int row = quad * 4 + r;
                float v0 = s0[r] + (float)bias_s[pb][row][ln][h];
                float v1 = s1[r] + (float)bias_s[pb][row][16 + ln][h];
                v0 = mm0 ? -1e30f : v0;
                v1 = mm1 ? -1e30f : v1;
                const float e0 = __expf(v0 - FIX_M);
                const float e1 = __expf(v1 - FIX_M);
                l_part[r] += e0 + e1;
                ps[h][row][ln]      = f2bf(e0);
                ps[h][row][16 + ln] = f2bf(e1);
            }
        }

        // ---- fence: ps writes drained; sched_barrier pins both sides (rule #18)
        __builtin_amdgcn_sched_barrier(0);
        asm volatile("s_waitcnt lgkmcnt(0)" ::: "memory");
        __builtin_amdgcn_sched_barrier(0);

        // ---- PV mfma (ps read is within-wave, now pinned after the fence) ----
        {
            short8 pa = *(const short8*)&ps[h][ln][quad * 8];
            #pragma unroll
            for (int nd = 0; nd < 4; ++nd)
                oacc[nd] = __builtin_amdgcn_mfma_f32_16x16x32_bf16(pa, vf[nd], oacc[nd], 0, 0, 0);
        }

        __syncthreads();   // single barrier: bias_s[(jt+1)&1] ready
    }

    // epilogue: reduce l over 16 lanes per row, O /= l, store bf16
    {
        float rl[4];
        #pragma unroll
        for (int r = 0; r < 4; ++r) {
            float l = l_part[r];
            l += __shfl_xor(l, 1, 64);
            l += __shfl_xor(l, 2, 64);
            l += __shfl_xor(l, 4, 64);
            l += __shfl_xor(l, 8, 64);
            rl[r] = 1.0f / l;
        }
        #pragma unroll
        for (int nd = 0; nd < 4; ++nd)
            #pragma unroll
            for (int r = 0; r < 4; ++r)
                attn_out[((size_t)b * NN + i0 + quad * 4 + r) * 512
                         + h * 64 + nd * 16 + ln] = f2bf(oacc[nd][r] * rl[r]);
    }
    #undef LOAD_CJ
    #undef MLP_TILE
}

extern "C" void kernel_launch(void* const* d_in, const int* in_sizes, int n_in,
                              void* d_out, int out_size, void* d_ws, size_t ws_size,
                              hipStream_t stream) {
    const float* x        = (const float*)d_in[0];
    const float* coords   = (const float*)d_in[1];
    const unsigned char* kpm = (const unsigned char*)d_in[2];
    const float* qkv_w    = (const float*)d_in[3];
    const float* out_w    = (const float*)d_in[4];
    const float* out_b    = (const float*)d_in[5];
    const float* alpha    = (const float*)d_in[6];
    const float* w1       = (const float*)d_in[7];
    const float* b1       = (const float*)d_in[8];
    const float* w2       = (const float*)d_in[9];
    const float* b2       = (const float*)d_in[10];
    const float* cscales  = (const float*)d_in[11];
    float* out = (float*)d_out;

    const int M = BB * NN;
    // workspace: Qb/Kb/Vt/Ao all bf16 = 4 x 8.39 MB = 33.6 MB
    unsigned short* Qb = (unsigned short*)d_ws;
    unsigned short* Kb = Qb + (size_t)M * D_MODEL;
    unsigned short* Vt = Kb + (size_t)M * D_MODEL;
    unsigned short* Ao = Vt + (size_t)M * D_MODEL;

    {
        dim3 grid(3 * D_MODEL / 128, M / 128);
        gemm_qkv_mfma<<<grid, 256, 0, stream>>>(x, qkv_w, Qb, Kb, Vt);
    }
    {
        dim3 grid(NN / TI, BB);
        attn_kernel<<<grid, 512, 0, stream>>>(Qb, Kb, Vt, coords, kpm, w1, b1, w2, b2,
                                              cscales, alpha, Ao);
    }
    {
        dim3 grid(D_MODEL / 128, M / 128);
        gemm_out_mfma<<<grid, 256, 0, stream>>>(Ao, out_w, out_b, out);
    }
}

// Round 7
// 365.324 us; speedup vs baseline: 1.2066x; 1.2066x over previous
//
#include <hip/hip_runtime.h>
#include <hip/hip_bf16.h>
#include <math.h>

#define D_MODEL 512
#define NHEAD   8
#define HEAD_DIM 64
#define BB      8
#define NN      1024
#define NS      1
#define TI      16
#define TJ      32
#define NT      (NN / TJ)
#define FIX_M   10.0f
#define GSTRIDE 40   // LDS row stride (shorts) for MFMA gemm tiles

typedef __attribute__((ext_vector_type(8))) short short8;
typedef __attribute__((ext_vector_type(4))) float floatx4;

// gelu, tanh form: 0.5x(1+tanh(0.79788(x+0.044715x^3))) = x*(1 - 1/(1+e^{2y}))
// 8 VALU ops, branch-free; |err vs erf-gelu| <= ~1e-3 absolute.
__device__ __forceinline__ float gelu_tanh(float x) {
    const float x2 = x * x;
    const float z  = x * fmaf(0.0713548162f, x2, 1.5957691216f);  // 2y
    const float e  = __expf(z);
    const float r  = __builtin_amdgcn_rcpf(1.0f + e);
    return fmaf(-x, r, x);
}

__device__ __forceinline__ unsigned short f2bf(float f) {
    unsigned u = __float_as_uint(f);
    u = (u + 0x7fffu + ((u >> 16) & 1u)) >> 16;   // RNE
    return (unsigned short)u;
}

__device__ __forceinline__ uint2 pack4bf(float a, float b, float c, float d) {
    uint2 p;
    p.x = (unsigned)f2bf(a) | ((unsigned)f2bf(b) << 16);
    p.y = (unsigned)f2bf(c) | ((unsigned)f2bf(d) << 16);
    return p;
}

// ---------------- bf16 MFMA GEMM: qkv = x @ qkv_w^T, fused bf16 epilogue ----
__global__ __launch_bounds__(256)
void gemm_qkv_mfma(const float* __restrict__ A, const float* __restrict__ Bm,
                   unsigned short* __restrict__ Qb, unsigned short* __restrict__ Kb,
                   unsigned short* __restrict__ Vt) {
    __shared__ __align__(16) unsigned short As[128 * GSTRIDE];
    __shared__ __align__(16) unsigned short Bs[128 * GSTRIDE];
    const int tid = threadIdx.x;
    const int bm = blockIdx.y * 128;
    const int bn = blockIdx.x * 128;
    const int wv = tid >> 6, lane = tid & 63, quad = lane >> 4, ln = lane & 15;
    const int wm = (wv >> 1) * 64, wn = (wv & 1) * 64;

    floatx4 acc[4][4];
    #pragma unroll
    for (int i = 0; i < 4; ++i)
        #pragma unroll
        for (int j = 0; j < 4; ++j) acc[i][j] = (floatx4){0.f, 0.f, 0.f, 0.f};

    for (int k0 = 0; k0 < 512; k0 += 32) {
        __syncthreads();
        #pragma unroll
        for (int t = 0; t < 4; ++t) {
            const int c = tid + t * 256;
            const int row = c >> 3, kc = (c & 7) * 4;
            float4 v = *(const float4*)(A + (size_t)(bm + row) * 512 + k0 + kc);
            *(uint2*)&As[row * GSTRIDE + kc] = pack4bf(v.x, v.y, v.z, v.w);
            float4 w = *(const float4*)(Bm + (size_t)(bn + row) * 512 + k0 + kc);
            *(uint2*)&Bs[row * GSTRIDE + kc] = pack4bf(w.x, w.y, w.z, w.w);
        }
        __syncthreads();
        short8 af[4], bf[4];
        #pragma unroll
        for (int mb = 0; mb < 4; ++mb)
            af[mb] = *(const short8*)&As[(wm + mb * 16 + ln) * GSTRIDE + quad * 8];
        #pragma unroll
        for (int nb = 0; nb < 4; ++nb)
            bf[nb] = *(const short8*)&Bs[(wn + nb * 16 + ln) * GSTRIDE + quad * 8];
        #pragma unroll
        for (int mb = 0; mb < 4; ++mb)
            #pragma unroll
            for (int nb = 0; nb < 4; ++nb)
                acc[mb][nb] = __builtin_amdgcn_mfma_f32_16x16x32_bf16(af[mb], bf[nb], acc[mb][nb], 0, 0, 0);
    }

    #pragma unroll
    for (int nb = 0; nb < 4; ++nb) {
        const int n = bn + wn + nb * 16 + ln;
        #pragma unroll
        for (int mb = 0; mb < 4; ++mb) {
            const int m = bm + wm + mb * 16 + quad * 4;
            if (n < 512) {
                #pragma unroll
                for (int r = 0; r < 4; ++r)
                    Qb[(size_t)(m + r) * 512 + n] = f2bf(acc[mb][nb][r] * 0.125f);
            } else if (n < 1024) {
                #pragma unroll
                for (int r = 0; r < 4; ++r)
                    Kb[(size_t)(m + r) * 512 + (n - 512)] = f2bf(acc[mb][nb][r]);
            } else {
                const int bb = m >> 10, tok = m & 1023;
                *(uint2*)(Vt + ((size_t)bb * 512 + (n - 1024)) * NN + tok) =
                    pack4bf(acc[mb][nb][0], acc[mb][nb][1], acc[mb][nb][2], acc[mb][nb][3]);
            }
        }
    }
}

// ---------------- bf16 MFMA GEMM: out = attn_out(bf16) @ out_w^T + out_b ----
__global__ __launch_bounds__(256)
void gemm_out_mfma(const unsigned short* __restrict__ Ab, const float* __restrict__ Bm,
                   const float* __restrict__ bias, float* __restrict__ C) {
    __shared__ __align__(16) unsigned short As[128 * GSTRIDE];
    __shared__ __align__(16) unsigned short Bs[128 * GSTRIDE];
    const int tid = threadIdx.x;
    const int bm = blockIdx.y * 128;
    const int bn = blockIdx.x * 128;
    const int wv = tid >> 6, lane = tid & 63, quad = lane >> 4, ln = lane & 15;
    const int wm = (wv >> 1) * 64, wn = (wv & 1) * 64;

    floatx4 acc[4][4];
    #pragma unroll
    for (int i = 0; i < 4; ++i)
        #pragma unroll
        for (int j = 0; j < 4; ++j) acc[i][j] = (floatx4){0.f, 0.f, 0.f, 0.f};

    for (int k0 = 0; k0 < 512; k0 += 32) {
        __syncthreads();
        #pragma unroll
        for (int t = 0; t < 4; ++t) {
            const int c = tid + t * 256;
            const int row = c >> 3, kc = (c & 7) * 4;
            *(uint2*)&As[row * GSTRIDE + kc] =
                *(const uint2*)(Ab + (size_t)(bm + row) * 512 + k0 + kc);
            float4 w = *(const float4*)(Bm + (size_t)(bn + row) * 512 + k0 + kc);
            *(uint2*)&Bs[row * GSTRIDE + kc] = pack4bf(w.x, w.y, w.z, w.w);
        }
        __syncthreads();
        short8 af[4], bf[4];
        #pragma unroll
        for (int mb = 0; mb < 4; ++mb)
            af[mb] = *(const short8*)&As[(wm + mb * 16 + ln) * GSTRIDE + quad * 8];
        #pragma unroll
        for (int nb = 0; nb < 4; ++nb)
            bf[nb] = *(const short8*)&Bs[(wn + nb * 16 + ln) * GSTRIDE + quad * 8];
        #pragma unroll
        for (int mb = 0; mb < 4; ++mb)
            #pragma unroll
            for (int nb = 0; nb < 4; ++nb)
                acc[mb][nb] = __builtin_amdgcn_mfma_f32_16x16x32_bf16(af[mb], bf[nb], acc[mb][nb], 0, 0, 0);
    }

    #pragma unroll
    for (int nb = 0; nb < 4; ++nb) {
        const int n = bn + wn + nb * 16 + ln;
        const float bv = bias[n];
        #pragma unroll
        for (int mb = 0; mb < 4; ++mb) {
            const int m = bm + wm + mb * 16 + quad * 4;
            #pragma unroll
            for (int r = 0; r < 4; ++r)
                C[(size_t)(m + r) * 512 + n] = acc[mb][nb][r] + bv;
        }
    }
}

// ---------------- MFMA flash attention: one head per wave --------------------
// Block = (b, 16 queries); 512 thr = 8 waves; wave wv owns head h=wv over ALL
// 32 j-tiles (no j-split -> no partial combine), and computes MLP rows
// i in {2wv, 2wv+1} (8 waves x 2 = 16 rows; total MLP work unchanged vs R0).
// REGISTER LAW (R2/R3/R6 post-mortems): every launch_bounds stricter than
// min-waves=2 made hipcc cap at <=128 (even 64) and spill catastrophically
// (R2: 3.7GB, R3: 0.85GB, R6: 0.29GB scratch traffic). ONLY min-waves=2
// (256-reg budget) allocates sanely. Residency must come from the NATURAL
// footprint: this one-head-per-wave body needs ~half of R5's frags
// (kf/vf 32, oacc 16 AGPR, qf 8) -> expected ~95-115 unified regs <= 128
// granule -> 4 waves/SIMD -> 2 blocks x 8 waves = 16 waves/CU (vs 8 in R0/R5).
// LDS 28 KB/block: 2 blocks = 57 KB, not limiting.
// Protocol is the VERIFIED R6 body (passed, absmax 3.9e-3): bias double-buffer
// + ONE barrier/iter (8 waves), ps fence idiom (rule #18), full 16-row MFMAs.
__global__ __launch_bounds__(512, 2)
void attn_kernel(const unsigned short* __restrict__ Qb,
                 const unsigned short* __restrict__ Kb,
                 const unsigned short* __restrict__ Vt,
                 const float* __restrict__ coords,
                 const unsigned char* __restrict__ mask,
                 const float* __restrict__ w1, const float* __restrict__ b1,
                 const float* __restrict__ w2, const float* __restrict__ b2,
                 const float* __restrict__ coord_scales,
                 const float* __restrict__ alpha_p,
                 unsigned short* __restrict__ attn_out) {
    const int b   = blockIdx.y;
    const int i0  = blockIdx.x * TI;
    const int tid = threadIdx.x;
    const int wv  = tid >> 6;        // 0..7 = this wave's head
    const int lane = tid & 63;
    const int quad = lane >> 4;
    const int ln   = lane & 15;
    const int h    = wv;

    __shared__ _Float16 bias_s[2][TI][TJ][9];                   // 18.0 KB
    __shared__ __align__(16) unsigned short ps[NHEAD][16][40];  // 10.0 KB

    const float alpha = alpha_p[0];
    const float isx = 1.0f / coord_scales[0];
    const float isy = 1.0f / coord_scales[1];
    const float isz = 1.0f / coord_scales[2];

    // this wave's 2 MLP query coords in registers (loop-invariant)
    float cir[2][3];
    #pragma unroll
    for (int g = 0; g < 2; ++g) {
        const float* cp = coords + ((size_t)b * NN + i0 + wv * 2 + g) * 3;
        cir[g][0] = cp[0] * isx; cir[g][1] = cp[1] * isy; cir[g][2] = cp[2] * isz;
    }

    // ---- per-lane MLP weight slice: units ku = quad*8+jj ----
    float4 w1r[8]; float b1r[8];
    #pragma unroll
    for (int jj = 0; jj < 8; ++jj) {
        w1r[jj] = *(const float4*)(w1 + (quad * 8 + jj) * 4);
        b1r[jj] = b1[quad * 8 + jj];
    }
    // w2 B-fragment: B[n=ln(head)][k=quad*8+jj] = alpha*w2, heads 8..15 -> 0
    short8 b2f;
    #pragma unroll
    for (int jj = 0; jj < 8; ++jj) {
        const float v = (ln < 8) ? alpha * w2[ln * 32 + quad * 8 + jj] : 0.0f;
        b2f[jj] = (short)f2bf(v);
    }
    const float ab2 = (ln < 8) ? alpha * b2[ln] : 0.0f;

    // Q A-fragments for this head (bf16, pre-scaled by 0.125)
    short8 qf[2];
    #pragma unroll
    for (int kd = 0; kd < 2; ++kd)
        qf[kd] = *(const short8*)(Qb + ((size_t)b * NN + i0 + ln) * 512
                                  + h * 64 + kd * 32 + quad * 8);

    floatx4 oacc[4];
    #pragma unroll
    for (int nd = 0; nd < 4; ++nd) oacc[nd] = (floatx4){0.f, 0.f, 0.f, 0.f};
    float l_part[4];
    #pragma unroll
    for (int r = 0; r < 4; ++r) l_part[r] = 0.f;

    const unsigned char* maskp = mask + (size_t)b * NN;
    float cjx[2], cjy[2], cjz[2];

    #define LOAD_CJ(tt_) do { const int tt = (tt_);                               \
        if (tt < NT) {                                                            \
            const float* cp0 = coords + ((size_t)b * NN + tt * TJ + ln) * 3;      \
            cjx[0] = cp0[0] * isx; cjy[0] = cp0[1] * isy; cjz[0] = cp0[2] * isz;  \
            cjx[1] = cp0[48] * isx; cjy[1] = cp0[49] * isy; cjz[1] = cp0[50] * isz; \
        } } while (0)

    // MLP for tile tt -> bias_s[tt&1]; 2 i-rows x 2 j-halves per wave.
    #define MLP_TILE(tt_) do { const int tt = (tt_);                              \
        if (tt < NT) {                                                            \
            const int pbw = tt & 1;                                               \
            const int j0m = tt * TJ;                                              \
            _Pragma("unroll")                                                     \
            for (int g = 0; g < 2; ++g) {                                         \
                const int i = wv * 2 + g;                                         \
                const float cix = cir[g][0], ciy = cir[g][1], ciz = cir[g][2];    \
                const bool irow0 = (i0 + i < NS);                                 \
                _Pragma("unroll")                                                 \
                for (int jh = 0; jh < 2; ++jh) {                                  \
                    const float dx = cix - cjx[jh];                               \
                    const float dy = ciy - cjy[jh];                               \
                    const float dz = ciz - cjz[jh];                               \
                    const float dist = sqrtf(dx * dx + dy * dy + dz * dz);        \
                    float hu[8];                                                  \
                    _Pragma("unroll")                                             \
                    for (int jj = 0; jj < 8; ++jj) {                              \
                        const float4 wa = w1r[jj];                                \
                        float t0v = fmaf(wa.x, dx, fmaf(wa.y, dy,                 \
                                    fmaf(wa.z, dz, fmaf(wa.w, dist, b1r[jj]))));  \
                        hu[jj] = gelu_tanh(t0v);                                  \
                    }                                                             \
                    union { short8 s8; unsigned u4[4]; } H;                       \
                    _Pragma("unroll")                                             \
                    for (int k = 0; k < 4; ++k) {                                 \
                        __hip_bfloat162 t2 = __float22bfloat162_rn(               \
                            make_float2(hu[2 * k], hu[2 * k + 1]));               \
                        H.u4[k] = *(unsigned*)&t2;                                \
                    }                                                             \
                    floatx4 D = __builtin_amdgcn_mfma_f32_16x16x32_bf16(          \
                        H.s8, b2f, (floatx4){0.f, 0.f, 0.f, 0.f}, 0, 0, 0);       \
                    if (ln < 8) {                                                 \
                        _Pragma("unroll")                                         \
                        for (int r = 0; r < 4; ++r) {                             \
                            const int jw = jh * 16 + quad * 4 + r;                \
                            const float val = (irow0 || (j0m + jw < NS))          \
                                              ? 0.0f : (D[r] + ab2);              \
                            bias_s[pbw][i][jw][ln] = (_Float16)val;               \
                        }                                                         \
                    }                                                             \
                }                                                                 \
            }                                                                     \
        } } while (0)

    // ---- prologue ----
    LOAD_CJ(0);
    MLP_TILE(0);
    __syncthreads();              // bias_s[0] ready

    for (int jt = 0; jt < NT; ++jt) {
        const int j0 = jt * TJ;
        const int pb = jt & 1;

        // ---- K/V/mask global loads for tile jt, this head (fly under MLP) ----
        short8 kf[4], vf[4];
        {
            const unsigned short* kbase = Kb + ((size_t)b * NN + j0) * 512 + h * 64;
            kf[0] = *(const short8*)(kbase + (size_t)ln * 512 + quad * 8);
            kf[1] = *(const short8*)(kbase + (size_t)ln * 512 + 32 + quad * 8);
            kf[2] = *(const short8*)(kbase + (size_t)(16 + ln) * 512 + quad * 8);
            kf[3] = *(const short8*)(kbase + (size_t)(16 + ln) * 512 + 32 + quad * 8);
            const unsigned short* vbase = Vt + ((size_t)b * 512 + h * 64) * NN + j0 + quad * 8;
            #pragma unroll
            for (int nd = 0; nd < 4; ++nd)
                vf[nd] = *(const short8*)(vbase + (size_t)(nd * 16 + ln) * NN);
        }
        const unsigned char mm0 = maskp[j0 + ln];
        const unsigned char mm1 = maskp[j0 + 16 + ln];

        // ---- MLP for tile jt+1 -> bias_s[(jt+1)&1] ----
        LOAD_CJ(jt + 1);
        MLP_TILE(jt + 1);

        // ---- QK mfma + bias + exp -> ps (reads bias_s[jt&1]; within-wave ps) ----
        {
            floatx4 s0 = (floatx4){0.f, 0.f, 0.f, 0.f};
            floatx4 s1 = (floatx4){0.f, 0.f, 0.f, 0.f};
            s0 = __builtin_amdgcn_mfma_f32_16x16x32_bf16(qf[0], kf[0], s0, 0, 0, 0);
            s0 = __builtin_amdgcn_mfma_f32_16x16x32_bf16(qf[1], kf[1], s0, 0, 0, 0);
            s1 = __builtin_amdgcn_mfma_f32_16x16x32_bf16(qf[0], kf[2], s1, 0, 0, 0);
            s1 = __builtin_amdgcn_mfma_f32_16x16x32_bf16(qf[1], kf[3], s1, 0, 0, 0);
            #pragma unroll
            for (int r = 0; r < 4; ++r) {
                const int row = quad * 4 + r;
                float v0 = s0[r] + (float)bias_s[pb][row][ln][h];
                float v1 = s1[r] + (float)bias_s[pb][row][16 + ln][h];
                v0 = mm0 ? -1e30f : v0;
                v1 = mm1 ? -1e30f : v1;
                const float e0 = __expf(v0 - FIX_M);
                const float e1 = __expf(v1 - FIX_M);
                l_part[r] += e0 + e1;
                ps[h][row][ln]      = f2bf(e0);
                ps[h][row][16 + ln] = f2bf(e1);
            }
        }

        // ---- fence: ps writes drained; sched_barrier pins both sides (rule #18)
        __builtin_amdgcn_sched_barrier(0);
        asm volatile("s_waitcnt lgkmcnt(0)" ::: "memory");
        __builtin_amdgcn_sched_barrier(0);

        // ---- PV mfma (ps read is within-wave, now pinned after the fence) ----
        {
            short8 pa = *(const short8*)&ps[h][ln][quad * 8];
            #pragma unroll
            for (int nd = 0; nd < 4; ++nd)
                oacc[nd] = __builtin_amdgcn_mfma_f32_16x16x32_bf16(pa, vf[nd], oacc[nd], 0, 0, 0);
        }

        __syncthreads();   // single barrier: bias_s[(jt+1)&1] ready
    }

    // epilogue: reduce l over 16 lanes per row, O /= l, store bf16
    {
        float rl[4];
        #pragma unroll
        for (int r = 0; r < 4; ++r) {
            float l = l_part[r];
            l += __shfl_xor(l, 1, 64);
            l += __shfl_xor(l, 2, 64);
            l += __shfl_xor(l, 4, 64);
            l += __shfl_xor(l, 8, 64);
            rl[r] = 1.0f / l;
        }
        #pragma unroll
        for (int nd = 0; nd < 4; ++nd)
            #pragma unroll
            for (int r = 0; r < 4; ++r)
                attn_out[((size_t)b * NN + i0 + quad * 4 + r) * 512
                         + h * 64 + nd * 16 + ln] = f2bf(oacc[nd][r] * rl[r]);
    }
    #undef LOAD_CJ
    #undef MLP_TILE
}

extern "C" void kernel_launch(void* const* d_in, const int* in_sizes, int n_in,
                              void* d_out, int out_size, void* d_ws, size_t ws_size,
                              hipStream_t stream) {
    const float* x        = (const float*)d_in[0];
    const float* coords   = (const float*)d_in[1];
    const unsigned char* kpm = (const unsigned char*)d_in[2];
    const float* qkv_w    = (const float*)d_in[3];
    const float* out_w    = (const float*)d_in[4];
    const float* out_b    = (const float*)d_in[5];
    const float* alpha    = (const float*)d_in[6];
    const float* w1       = (const float*)d_in[7];
    const float* b1       = (const float*)d_in[8];
    const float* w2       = (const float*)d_in[9];
    const float* b2       = (const float*)d_in[10];
    const float* cscales  = (const float*)d_in[11];
    float* out = (float*)d_out;

    const int M = BB * NN;
    // workspace: Qb/Kb/Vt/Ao all bf16 = 4 x 8.39 MB = 33.6 MB
    unsigned short* Qb = (unsigned short*)d_ws;
    unsigned short* Kb = Qb + (size_t)M * D_MODEL;
    unsigned short* Vt = Kb + (size_t)M * D_MODEL;
    unsigned short* Ao = Vt + (size_t)M * D_MODEL;

    {
        dim3 grid(3 * D_MODEL / 128, M / 128);
        gemm_qkv_mfma<<<grid, 256, 0, stream>>>(x, qkv_w, Qb, Kb, Vt);
    }
    {
        dim3 grid(NN / TI, BB);
        attn_kernel<<<grid, 512, 0, stream>>>(Qb, Kb, Vt, coords, kpm, w1, b1, w2, b2,
                                              cscales, alpha, Ao);
    }
    {
        dim3 grid(D_MODEL / 128, M / 128);
        gemm_out_mfma<<<grid, 256, 0, stream>>>(Ao, out_w, out_b, out);
    }
}